// Round 11
// baseline (228.428 us; speedup 1.0000x reference)
//
#include <hip/hip_runtime.h>
#include <math.h>

// hybridDynamicSimNew: B=65536 cars, H=5, F=50. One thread/car.
//
// R10 (resubmitted unchanged -- broker timeout, never measured):
// STOP fighting for weight residency. Six rounds of evidence
// (VGPR_Count 244/236/136/104/60/76 across every residency trick) show the
// allocator will not keep a large weight set live, and the resulting
// scratch/LDS re-read stalls at 1 wave/SIMD dominate (R9: 30% VALU, 7% MFMA,
// ~3600cy/substep idle). Also: CDNA arch-VGPR cap is 256/wave -- the 400-f32
// plan never fit. This version EMBRACES per-step LDS re-reads:
//  - fc1 weights in LDS, k-major; per k one base + immediate-offset
//    4x ds_read_b128, wave-uniform address -> conflict-free broadcast,
//    ZERO address VALU.
//  - GEMV: y1_o = fmaf(feat[k], q, y1_o) -- feat[k] is one shared VGPR
//    operand (no splat movs, R4's hidden 800cy/step cost).
//  - b1/w2/b2/params in SGPRs (rfl), folded as the 1 allowed SGPR operand.
//  - asm ::: "memory" clobber at top of outer loop blocks LICM from
//    hoisting the loop-invariant weight reads (inverse failure mode).
// Live set ~100 regs -- comfortable under any allocator budget.
// Numerics = R4 exactly (f32 weights, absmax 0.0273 passed).
// Planned fallback if LDS-pipe-bound (VALUBusy<50%, dur ~100us): packed-f16
// weight pairs + v_fma_mix (halves LDS traffic; f16 weights passed in R6).

__device__ __forceinline__ float rfl(float x) {
    return __int_as_float(__builtin_amdgcn_readfirstlane(__float_as_int(x)));
}

__device__ __forceinline__ float fast_tanhf(float x) {
    float e = __builtin_amdgcn_exp2f(x * 2.8853900817779268f);
    return 1.0f - 2.0f * __builtin_amdgcn_rcpf(e + 1.0f);
}

// sin(x) for |x| <= ~0.16 (tire model: |tC*atan| <= 0.1*pi/2)
__device__ __forceinline__ float sin_small(float x) {
    float x2 = x * x;
    return x * (1.0f + x2 * (-1.66666667e-1f + x2 * 8.33333338e-3f));
}

// branchless full-range atan, max err ~1.5e-6 rad
__device__ __forceinline__ float fatanf(float x) {
    float ax = fabsf(x);
    bool big = ax > 1.0f;
    float z  = big ? __builtin_amdgcn_rcpf(ax) : ax;
    float z2 = z * z;
    float p = fmaf(z2, -0.0117212f, 0.05265332f);
    p = fmaf(z2, p, -0.11643287f);
    p = fmaf(z2, p,  0.19354346f);
    p = fmaf(z2, p, -0.33262347f);
    p = fmaf(z2, p,  0.99997726f);
    float r = z * p;
    r = big ? (1.57079632679489662f - r) : r;
    return copysignf(r, x);
}

__global__ __launch_bounds__(256, 1)
void sim_kernel(const float* __restrict__ fs,   // (B,5,8)
                const float* __restrict__ act,  // (B,50,2)
                const float* __restrict__ w1,   // (16,25) [o][k]
                const float* __restrict__ b1,   // (16)
                const float* __restrict__ w2,   // (3,16)
                const float* __restrict__ b2,   // (3)
                const float* __restrict__ prm,  // (10)
                const int*   __restrict__ rnnp, // (1)
                float* __restrict__ out)        // (B,50,8)
{
    __shared__ float sW1t[400];  // k-major: sW1t[k*16+o] = w1[o][k]

    const int tid = threadIdx.x;
    for (int i = tid; i < 400; i += 256) {
        int o = i & 15;
        int k = i >> 4;
        sW1t[i] = w1[o * 25 + k];
    }
    __syncthreads();

    const int b = blockIdx.x * 256 + tid;

    const float4* fsp = reinterpret_cast<const float4*>(fs + (size_t)b * 40);
    const float4* ap  = reinterpret_cast<const float4*>(act + (size_t)b * 100);
    float4 acur = ap[0];

    float wf[40];
#pragma unroll
    for (int i = 0; i < 10; ++i) {
        float4 v = fsp[i];
        wf[i * 4 + 0] = v.x; wf[i * 4 + 1] = v.y;
        wf[i * 4 + 2] = v.z; wf[i * 4 + 3] = v.w;
    }

    // wave-uniform params -> SGPR
    const float lf = rfl(prm[0]), lr = rfl(prm[1]), mIz = rfl(prm[2]);
    const float cm1 = rfl(prm[3]), cm2 = rfl(prm[4]), cr = rfl(prm[5]);
    const float cd = rfl(prm[6]);
    const float tB = rfl(prm[7]), tC = rfl(prm[8]), tD = rfl(prm[9]);
    const int   rnn = __builtin_amdgcn_readfirstlane(rnnp[0]);
    const float dt = 0.01f;
    const float PI = 3.14159265358979323846f;
    const float INV2PI = 0.15915494309189535f;
    const float TWOPI = 6.28318530717958647692f;

    // b1, fc2 weights, b2 -> SGPR scalars (folded into FMAs as SGPR src)
#define DECLB1(K) const float b1s_##K = rfl(b1[(K)]);
    DECLB1(0) DECLB1(1) DECLB1(2) DECLB1(3)
    DECLB1(4) DECLB1(5) DECLB1(6) DECLB1(7)
    DECLB1(8) DECLB1(9) DECLB1(10) DECLB1(11)
    DECLB1(12) DECLB1(13) DECLB1(14) DECLB1(15)
#undef DECLB1
#define DECLW2(K) \
    const float w2a_##K = rfl(w2[(K)]);      \
    const float w2b_##K = rfl(w2[16 + (K)]); \
    const float w2c_##K = rfl(w2[32 + (K)]);
    DECLW2(0) DECLW2(1) DECLW2(2) DECLW2(3)
    DECLW2(4) DECLW2(5) DECLW2(6) DECLW2(7)
    DECLW2(8) DECLW2(9) DECLW2(10) DECLW2(11)
    DECLW2(12) DECLW2(13) DECLW2(14) DECLW2(15)
#undef DECLW2
    const float b2s0 = rfl(b2[0]), b2s1 = rfl(b2[1]), b2s2 = rfl(b2[2]);

    // ---- initial feature window ----
    // feat: [Vxh(0..4), Vyh(5..9), omega(10..14), thr(15..19), steer(20..24)]
    float feat[25];
#pragma unroll
    for (int t = 0; t < 5; ++t) {
        float ph = wf[t * 8 + 4];
        float ch = __cosf(ph), sh = __sinf(ph);
        float v1 = wf[t * 8 + 1], v3 = wf[t * 8 + 3];
        feat[t]      =  v1 * ch + v3 * sh;
        feat[5 + t]  = -v1 * sh + v3 * ch;
        feat[10 + t] = wf[t * 8 + 5];
        feat[15 + t] = wf[t * 8 + 6];
        feat[20 + t] = wf[t * 8 + 7];
    }

    float x   = wf[32];
    float y   = wf[34];
    float psi = wf[36];
    float c = __cosf(psi), s = __sinf(psi);

    const float4* wkp = reinterpret_cast<const float4*>(sW1t);
    float* outp = out + (size_t)b * 400;

#pragma unroll 1
    for (int f2 = 0; f2 < 25; ++f2) {
        // Block LICM: weight reads must stay inside the loop (hoisting all
        // 400 floats would force spills -- the R4-R9 failure mode).
        asm volatile("" ::: "memory");

        float4 anext = ap[(f2 < 24) ? (f2 + 1) : 24];

#pragma unroll
        for (int half = 0; half < 2; ++half) {
            const float a0 = half ? acur.z : acur.x;
            const float a1 = half ? acur.w : acur.y;

            // ---- physics ----
            const float throttle = feat[19];
            const float steering = feat[24];
            const float Vx = feat[4];
            const float Vy = feat[9];

            const float atr    = fatanf(Vy * __builtin_amdgcn_rcpf(Vx));
            const float slip_f = -atr + steering;
            const float slip_r = -atr;
            const float laf = tD * sin_small(tC * fatanf(tB * slip_f));
            const float lar = tD * sin_small(tC * fatanf(tB * slip_r));

            const float st_s = __sinf(steering), st_c = __cosf(steering);
            const float fwd  = (cm1 - cm2 * Vx) * throttle - cr - cd * Vx * Vx;

            float Vx2   = Vx + (fwd - laf * st_s) * dt;
            float Vy2   = Vy + (lar + laf * st_c) * dt;
            float omega = mIz * (laf * lf * st_c - lar * lr) * dt;

            // ---- RNN (wave-uniform branch) ----
            if (rnn) {
                float y1_0, y1_1, y1_2, y1_3, y1_4, y1_5, y1_6, y1_7,
                      y1_8, y1_9, y1_10, y1_11, y1_12, y1_13, y1_14, y1_15;
                // k=0: fold b1 (SGPR) into the first FMA
                {
                    const float4 q0 = wkp[0], q1 = wkp[1];
                    const float4 q2 = wkp[2], q3 = wkp[3];
                    const float f0 = feat[0];
                    y1_0  = fmaf(f0, q0.x, b1s_0);
                    y1_1  = fmaf(f0, q0.y, b1s_1);
                    y1_2  = fmaf(f0, q0.z, b1s_2);
                    y1_3  = fmaf(f0, q0.w, b1s_3);
                    y1_4  = fmaf(f0, q1.x, b1s_4);
                    y1_5  = fmaf(f0, q1.y, b1s_5);
                    y1_6  = fmaf(f0, q1.z, b1s_6);
                    y1_7  = fmaf(f0, q1.w, b1s_7);
                    y1_8  = fmaf(f0, q2.x, b1s_8);
                    y1_9  = fmaf(f0, q2.y, b1s_9);
                    y1_10 = fmaf(f0, q2.z, b1s_10);
                    y1_11 = fmaf(f0, q2.w, b1s_11);
                    y1_12 = fmaf(f0, q3.x, b1s_12);
                    y1_13 = fmaf(f0, q3.y, b1s_13);
                    y1_14 = fmaf(f0, q3.z, b1s_14);
                    y1_15 = fmaf(f0, q3.w, b1s_15);
                }
#define GK(K)                                                         \
                {                                                     \
                    const float4 q0 = wkp[(K) * 4 + 0];               \
                    const float4 q1 = wkp[(K) * 4 + 1];               \
                    const float4 q2 = wkp[(K) * 4 + 2];               \
                    const float4 q3 = wkp[(K) * 4 + 3];               \
                    const float fk = feat[(K)];                       \
                    y1_0  = fmaf(fk, q0.x, y1_0);                     \
                    y1_1  = fmaf(fk, q0.y, y1_1);                     \
                    y1_2  = fmaf(fk, q0.z, y1_2);                     \
                    y1_3  = fmaf(fk, q0.w, y1_3);                     \
                    y1_4  = fmaf(fk, q1.x, y1_4);                     \
                    y1_5  = fmaf(fk, q1.y, y1_5);                     \
                    y1_6  = fmaf(fk, q1.z, y1_6);                     \
                    y1_7  = fmaf(fk, q1.w, y1_7);                     \
                    y1_8  = fmaf(fk, q2.x, y1_8);                     \
                    y1_9  = fmaf(fk, q2.y, y1_9);                     \
                    y1_10 = fmaf(fk, q2.z, y1_10);                    \
                    y1_11 = fmaf(fk, q2.w, y1_11);                    \
                    y1_12 = fmaf(fk, q3.x, y1_12);                    \
                    y1_13 = fmaf(fk, q3.y, y1_13);                    \
                    y1_14 = fmaf(fk, q3.z, y1_14);                    \
                    y1_15 = fmaf(fk, q3.w, y1_15);                    \
                }
                GK(1) GK(2) GK(3) GK(4)
                GK(5) GK(6) GK(7) GK(8) GK(9)
                GK(10) GK(11) GK(12) GK(13) GK(14)
                GK(15) GK(16) GK(17) GK(18) GK(19)
                GK(20) GK(21) GK(22) GK(23) GK(24)
#undef GK

                float z0 = b2s0, z1 = b2s1, z2 = b2s2;
#define FC2(K)                                       \
                {                                    \
                    float t_ = fast_tanhf(y1_##K);   \
                    z0 = fmaf(t_, w2a_##K, z0);      \
                    z1 = fmaf(t_, w2b_##K, z1);      \
                    z2 = fmaf(t_, w2c_##K, z2);      \
                }
                FC2(0) FC2(1) FC2(2) FC2(3)
                FC2(4) FC2(5) FC2(6) FC2(7)
                FC2(8) FC2(9) FC2(10) FC2(11)
                FC2(12) FC2(13) FC2(14) FC2(15)
#undef FC2
                Vx2   += fast_tanhf(z0) * 5.0f * dt;
                Vy2   += fast_tanhf(z1) * 5.0f * dt;
                omega += fast_tanhf(z2) * 3.0f * dt;
            }

            // ---- global-frame update ----
            const float Vxg = Vx2 * c - Vy2 * s;
            const float Vyg = Vx2 * s + Vy2 * c;
            float pn = psi + omega * dt + PI;
            pn = pn - floorf(pn * INV2PI) * TWOPI - PI;

            x = x + Vxg * dt;
            y = y + Vyg * dt;

            float4 o0 = make_float4(x, Vxg, y, Vyg);
            float4 o1 = make_float4(pn, omega, a0, a1);
            reinterpret_cast<float4*>(outp)[0] = o0;
            reinterpret_cast<float4*>(outp)[1] = o1;
            outp += 8;

            // ---- advance / shift window ----
            psi = pn;
            c = __cosf(pn);
            s = __sinf(pn);
#pragma unroll
            for (int j = 0; j < 5; ++j)
#pragma unroll
                for (int t = 0; t < 4; ++t)
                    feat[j * 5 + t] = feat[j * 5 + t + 1];
            feat[4]  =  Vxg * c + Vyg * s;
            feat[9]  = -Vxg * s + Vyg * c;
            feat[14] = omega;
            feat[19] = a0;
            feat[24] = a1;
        }
        acur = anext;
    }
}

extern "C" void kernel_launch(void* const* d_in, const int* in_sizes, int n_in,
                              void* d_out, int out_size, void* d_ws, size_t ws_size,
                              hipStream_t stream) {
    const float* fs  = (const float*)d_in[0];
    const float* act = (const float*)d_in[1];
    const float* w1  = (const float*)d_in[2];
    const float* b1  = (const float*)d_in[3];
    const float* w2  = (const float*)d_in[4];
    const float* b2  = (const float*)d_in[5];
    const float* prm = (const float*)d_in[6];
    const int*   rnn = (const int*)d_in[7];
    float* out = (float*)d_out;

    const int Bn = in_sizes[0] / 40;  // 65536 cars, 1 thread each
    dim3 grid(Bn / 256), block(256);
    hipLaunchKernelGGL(sim_kernel, grid, block, 0, stream,
                       fs, act, w1, b1, w2, b2, prm, rnn, out);
}